// Round 8
// baseline (589.892 us; speedup 1.0000x reference)
//
#include <hip/hip_runtime.h>
#include <hip/hip_bf16.h>

typedef __attribute__((ext_vector_type(4))) float f32x4;
typedef __attribute__((ext_vector_type(8))) short bf16x8;

#define EDGE_GRID 1792
#define OUT_GRID  1024

// RNE f32->bf16 via scalar casts: compiler fuses pairs to v_cvt_pk_bf16_f32
__device__ __forceinline__ unsigned int packbf(float lo, float hi) {
    __hip_bfloat16 l = __float2bfloat16(lo), h = __float2bfloat16(hi);
    const unsigned short lu = *reinterpret_cast<unsigned short*>(&l);
    const unsigned short hu = *reinterpret_cast<unsigned short*>(&h);
    return (unsigned int)lu | ((unsigned int)hu << 16);
}
__device__ __forceinline__ unsigned short bf1(float f) {
    __hip_bfloat16 v = __float2bfloat16(f);
    return *reinterpret_cast<unsigned short*>(&v);
}

// ---------------------------------------------------------------------------
// mega-prep: [0,NB_X) xbf = bf16(x); [NB_X,+NB_C) deg histogram;
//            [+NB_C,+224) W2t/Wgt/W1at transposes.
// ---------------------------------------------------------------------------
__global__ __launch_bounds__(256) void prep_kernel(
    const float* __restrict__ x, const float* __restrict__ W1,
    const float* __restrict__ W2, const float* __restrict__ Wg,
    const int* __restrict__ ei, unsigned short* __restrict__ xbf,
    unsigned short* __restrict__ W2t, unsigned short* __restrict__ Wgt,
    unsigned short* __restrict__ W1at, int* __restrict__ deg,
    int N64, int E, int nTot, int NB_X, int NB_C)
{
    const int blk = blockIdx.x, t = threadIdx.x;
    if (blk < NB_X) {
        const int idx = blk * 2048 + t * 8;
        if (idx < N64) {
            const float4 f0 = *(const float4*)(x + idx);
            const float4 f1 = *(const float4*)(x + idx + 4);
            int4 o;
            o.x = (int)packbf(f0.x, f0.y); o.y = (int)packbf(f0.z, f0.w);
            o.z = (int)packbf(f1.x, f1.y); o.w = (int)packbf(f1.z, f1.w);
            *(int4*)(xbf + idx) = o;
        }
    } else if (blk < NB_X + NB_C) {
        const int i = (blk - NB_X) * 256 + t;
        if (i < nTot) atomicAdd(deg + ((i < E) ? ei[i] : i - E), 1);
    } else {
        const int i = (blk - NB_X - NB_C) * 256 + t;
        if (i < 16384) {                       // W2t[n][k] = W2[k][n]
            W2t[i] = bf1(W2[(i & 127) * 128 + (i >> 7)]);
        } else if (i < 49152) {                // Wgt[n][k] = Wg[k][n]
            const int j = i - 16384;
            Wgt[j] = bf1(Wg[(j & 127) * 256 + (j >> 7)]);
        } else if (i < 57344) {                // W1at[n][k] = W1[k][n], k<64
            const int j = i - 49152;
            W1at[j] = bf1(W1[(j & 63) * 128 + (j >> 6)]);
        }
    }
}

// ---------------------------------------------------------------------------
// Single-block exclusive scan of deg[N] -> offs[N].  1024 thr x 52 elems.
// ---------------------------------------------------------------------------
__global__ __launch_bounds__(1024) void scan_kernel(
    const int* __restrict__ deg, int* __restrict__ offs, int N)
{
    __shared__ int sc[1024];
    const int t = threadIdx.x;
    const int c0 = t * 52;
    int v[52];
    int s = 0;
#pragma unroll
    for (int j4 = 0; j4 < 13; ++j4) {
        const int idx = c0 + j4 * 4;
        int4 d = {0, 0, 0, 0};
        if (idx + 3 < N) d = *(const int4*)(deg + idx);
        else {
            if (idx     < N) d.x = deg[idx];
            if (idx + 1 < N) d.y = deg[idx + 1];
            if (idx + 2 < N) d.z = deg[idx + 2];
        }
        v[j4*4+0] = s; s += d.x;
        v[j4*4+1] = s; s += d.y;
        v[j4*4+2] = s; s += d.z;
        v[j4*4+3] = s; s += d.w;
    }
    sc[t] = s;
    __syncthreads();
    for (int off = 1; off < 1024; off <<= 1) {
        const int val = (t >= off) ? sc[t - off] : 0;
        __syncthreads();
        sc[t] += val;
        __syncthreads();
    }
    const int base = sc[t] - s;
#pragma unroll
    for (int j4 = 0; j4 < 13; ++j4) {
        const int idx = c0 + j4 * 4;
        const int4 o = {base + v[j4*4], base + v[j4*4+1], base + v[j4*4+2], base + v[j4*4+3]};
        if (idx + 3 < N) *(int4*)(offs + idx) = o;
        else {
            if (idx     < N) offs[idx]     = o.x;
            if (idx + 1 < N) offs[idx + 1] = o.y;
            if (idx + 2 < N) offs[idx + 2] = o.z;
        }
    }
}

// ---------------------------------------------------------------------------
// scatter: deg doubles as cursor via atomicSub; packed (row,col) int2.
// ---------------------------------------------------------------------------
__global__ void scatter_kernel(const int* __restrict__ ei, const int* __restrict__ offs,
                               int* __restrict__ deg, int2* __restrict__ spair,
                               int E, int nTot)
{
    const int i = blockIdx.x * 256 + threadIdx.x;
    if (i < nTot) {
        int row, col;
        if (i < E) { row = ei[i]; col = ei[E + i]; }
        else       { row = col = i - E; }
        const int p = atomicSub(deg + row, 1) - 1;
        spair[offs[row] + p] = make_int2(row, col);
    }
}

// ---------------------------------------------------------------------------
// Fused edge MLP, both layers as bf16 MFMA, + segmented scatter-max.
//  MFMA-1: h1 = x[col] @ W1a (K=64, B-frags in regs)
//  finish: h1 = relu(h1 + rel*W1p + b1)  (f32 VALU, rel stays f32)
//  MFMA-2: h2 = relu(h1 @ W2 + b2) -> bf16 in sh2u
// LDS ~21 KB -> 7 blocks/CU.  Gather traffic: 128 B/edge (x bf16).
// ---------------------------------------------------------------------------
__global__ __launch_bounds__(256, 7) void edge_kernel(
    const unsigned short* __restrict__ xbf, const float* __restrict__ pos,
    const float* __restrict__ W1, const float* __restrict__ b1,
    const float* __restrict__ b2, const unsigned short* __restrict__ W2t,
    const unsigned short* __restrict__ W1at, const int2* __restrict__ spair,
    unsigned int* __restrict__ agg, int nTot, int nTiles)
{
    __shared__ unsigned short sx1[2048];   // [32 e][64 k] bf16, granule^(e&7)
    __shared__ unsigned short sh1b[4096];  // [32 e][128 h] bf16, granule^(e&7)
    __shared__ unsigned short sh2u[4096];  // [32 e][128 n] bf16, col rot +2e
    __shared__ float4 sRel4[32];
    __shared__ int sRowL[2][32];

    const int t = threadIdx.x;
    const int wv = t >> 6, lane = t & 63;
    const int m = lane & 15, g = lane >> 4;
    const int n0 = wv * 32 + m;
    const int e8 = t >> 3, j8 = t & 7;
    const int cR = t & 127, hR = t >> 7;

    // W2 + W1a fragments and per-col constants -> registers
    bf16x8 bfrW2[2][4], bfrA[2][2];
    float w1pv[2][3], b1v[2], b2v[2];
#pragma unroll
    for (int nb = 0; nb < 2; ++nb) {
        const int n = n0 + nb * 16;
#pragma unroll
        for (int ks = 0; ks < 4; ++ks)
            bfrW2[nb][ks] = *(const bf16x8*)(W2t + (size_t)n * 128 + (ks * 4 + g) * 8);
#pragma unroll
        for (int ks = 0; ks < 2; ++ks)
            bfrA[nb][ks] = *(const bf16x8*)(W1at + (size_t)n * 64 + (ks * 4 + g) * 8);
#pragma unroll
        for (int ax = 0; ax < 3; ++ax)
            w1pv[nb][ax] = W1[(64 + ax) * 128 + n];
        b1v[nb] = b1[n];
        b2v[nb] = b2[n];
    }

    auto gatherX = [&](int tile, uint4& xa, float& r0, float& r1, float& r2, int& rowStage) {
        xa = make_uint4(0, 0, 0, 0); r0 = r1 = r2 = 0.0f; rowStage = -1;
        if (tile < nTiles) {
            const int p = tile * 32 + e8;
            if (p < nTot) {
                const int2 pr = spair[p];                      // (row, col)
                xa = *(const uint4*)(xbf + (size_t)pr.y * 64 + j8 * 8);
                if (j8 == 0) {
                    r0 = pos[pr.y * 3 + 0] - pos[pr.x * 3 + 0];
                    r1 = pos[pr.y * 3 + 1] - pos[pr.x * 3 + 1];
                    r2 = pos[pr.y * 3 + 2] - pos[pr.x * 3 + 2];
                }
            }
            if (t < 32) {
                const int p2 = tile * 32 + t;
                rowStage = (p2 < nTot) ? spair[p2].x : -1;
            }
        }
    };
    auto stage = [&](int buf, const uint4& xa, float r0, float r1, float r2, int rowStage) {
        ((uint4*)sx1)[e8 * 8 + (j8 ^ (e8 & 7))] = xa;
        if (j8 == 0) sRel4[e8] = make_float4(r0, r1, r2, 0.0f);
        if (t < 32) sRowL[buf][t] = rowStage;
    };

    // prologue
    {
        uint4 xa; float r0, r1, r2; int rs;
        gatherX(blockIdx.x, xa, r0, r1, r2, rs);
        stage(0, xa, r0, r1, r2, rs);
    }
    __syncthreads();

    int b = 0;
    for (int tile = blockIdx.x; tile < nTiles; tile += EDGE_GRID, b ^= 1) {
        // ---- A: issue next tile's gathers (hidden under MFMA phases)
        uint4 xa; float r0, r1, r2; int rs;
        gatherX(tile + EDGE_GRID, xa, r0, r1, r2, rs);

        // ---- MFMA-1: h1 = x @ W1a  (K=64)
        f32x4 h1a[2][2] = {{{0,0,0,0},{0,0,0,0}}, {{0,0,0,0},{0,0,0,0}}};
#pragma unroll
        for (int ks = 0; ks < 2; ++ks) {
            const int slot = ks * 4 + g;
            const bf16x8 a0 = *(const bf16x8*)&sx1[(m        * 8 + (slot ^ (m & 7))) << 3];
            const bf16x8 a1 = *(const bf16x8*)&sx1[((m + 16) * 8 + (slot ^ (m & 7))) << 3];
            h1a[0][0] = __builtin_amdgcn_mfma_f32_16x16x32_bf16(a0, bfrA[0][ks], h1a[0][0], 0, 0, 0);
            h1a[0][1] = __builtin_amdgcn_mfma_f32_16x16x32_bf16(a0, bfrA[1][ks], h1a[0][1], 0, 0, 0);
            h1a[1][0] = __builtin_amdgcn_mfma_f32_16x16x32_bf16(a1, bfrA[0][ks], h1a[1][0], 0, 0, 0);
            h1a[1][1] = __builtin_amdgcn_mfma_f32_16x16x32_bf16(a1, bfrA[1][ks], h1a[1][1], 0, 0, 0);
        }
        // finish h1: + rel*W1p + b1, relu, pack bf16 into sh1b (swizzled)
#pragma unroll
        for (int hf = 0; hf < 2; ++hf)
#pragma unroll
        for (int rg = 0; rg < 4; ++rg) {
            const int e = hf * 16 + g * 4 + rg;
            const float4 rv = sRel4[e];
#pragma unroll
            for (int nb = 0; nb < 2; ++nb) {
                float h = h1a[hf][nb][rg] + rv.x * w1pv[nb][0] + rv.y * w1pv[nb][1]
                        + rv.z * w1pv[nb][2] + b1v[nb];
                h = fmaxf(h, 0.0f);
                const int hcol = n0 + nb * 16;
                sh1b[((e * 16 + ((hcol >> 3) ^ (e & 7))) << 3) + (hcol & 7)] = bf1(h);
            }
        }
        __syncthreads();   // sh1b ready; sx1/sRel4 free

        // ---- MFMA-2: h2 = relu(h1 @ W2 + b2) -> sh2u (bf16, rotated cols)
        {
            f32x4 acc[2][2] = {{{0,0,0,0},{0,0,0,0}}, {{0,0,0,0},{0,0,0,0}}};
#pragma unroll
            for (int ks = 0; ks < 4; ++ks) {
                const int slot = ks * 4 + g;
                const bf16x8 a0 = *(const bf16x8*)&sh1b[(m        * 16 + (slot ^ (m & 7))) << 3];
                const bf16x8 a1 = *(const bf16x8*)&sh1b[((m + 16) * 16 + (slot ^ (m & 7))) << 3];
                acc[0][0] = __builtin_amdgcn_mfma_f32_16x16x32_bf16(a0, bfrW2[0][ks], acc[0][0], 0, 0, 0);
                acc[0][1] = __builtin_amdgcn_mfma_f32_16x16x32_bf16(a0, bfrW2[1][ks], acc[0][1], 0, 0, 0);
                acc[1][0] = __builtin_amdgcn_mfma_f32_16x16x32_bf16(a1, bfrW2[0][ks], acc[1][0], 0, 0, 0);
                acc[1][1] = __builtin_amdgcn_mfma_f32_16x16x32_bf16(a1, bfrW2[1][ks], acc[1][1], 0, 0, 0);
            }
#pragma unroll
            for (int hf = 0; hf < 2; ++hf)
#pragma unroll
            for (int rg = 0; rg < 4; ++rg) {
                const int e = hf * 16 + g * 4 + rg;
#pragma unroll
                for (int nb = 0; nb < 2; ++nb) {
                    const float v = fmaxf(acc[hf][nb][rg] + b2v[nb], 0.0f);
                    sh2u[e * 128 + ((n0 + nb * 16 + 2 * e) & 127)] = bf1(v);
                }
            }
        }

        // ---- D: stage next tile (sx1/sRel4 free since barrier above)
        stage(b ^ 1, xa, r0, r1, r2, rs);
        __syncthreads();   // sh2u + next stage ready

        // ---- C: segmented max over sorted rows + guarded atomicMax
        {
            float run = 0.0f; int cur = -1;
            const int ebase = hR * 16;
            for (int i = 0; i < 16; ++i) {
                const int e = ebase + i;
                const int r = sRowL[b][e];
                if (r < 0) break;
                const unsigned short hv = sh2u[e * 128 + ((cR + 2 * e) & 127)];
                const float v = __uint_as_float((unsigned int)hv << 16);
                if (r != cur) {
                    if (cur >= 0) {
                        const unsigned int bits = __float_as_uint(run);
                        unsigned int* dst = agg + (size_t)cur * 128 + cR;
                        if (bits > *dst) atomicMax(dst, bits);
                    }
                    cur = r; run = v;
                } else run = fmaxf(run, v);
            }
            if (cur >= 0) {
                const unsigned int bits = __float_as_uint(run);
                unsigned int* dst = agg + (size_t)cur * 128 + cR;
                if (bits > *dst) atomicMax(dst, bits);
            }
        }
    }
}

// ---------------------------------------------------------------------------
// out = relu(agg @ Wg + bg) via bf16 MFMA; Wg fragments in registers.
// ---------------------------------------------------------------------------
__global__ __launch_bounds__(256, 4) void out_kernel(
    const float* __restrict__ agg, const unsigned short* __restrict__ Wgt,
    const float* __restrict__ bg, float* __restrict__ out, int N, int nTiles)
{
    __shared__ unsigned short sA[4096];   // [32 e][128 k] bf16, granule^(e&7)

    const int t = threadIdx.x;
    const int wv = t >> 6, lane = t & 63;
    const int m = lane & 15, g = lane >> 4;
    const int eA = t >> 3, kcA = (t & 7) * 16;

    bf16x8 wfr[4][4];
    float bgv[4];
#pragma unroll
    for (int nt = 0; nt < 4; ++nt) {
        const int n = wv * 64 + nt * 16 + m;
#pragma unroll
        for (int ks = 0; ks < 4; ++ks)
            wfr[nt][ks] = *(const bf16x8*)(Wgt + (size_t)n * 128 + (ks * 4 + g) * 8);
        bgv[nt] = bg[n];
    }

    for (int tile = blockIdx.x; tile < nTiles; tile += OUT_GRID) {
        const int tbase = tile * 32;
        {
            unsigned int ow[8] = {0,0,0,0,0,0,0,0};
            const int node = tbase + eA;
            if (node < N) {
                const float4* ap = (const float4*)(agg + (size_t)node * 128 + kcA);
#pragma unroll
                for (int j = 0; j < 4; ++j) {
                    const float4 v = ap[j];
                    ow[j * 2 + 0] = packbf(v.x, v.y);
                    ow[j * 2 + 1] = packbf(v.z, v.w);
                }
            }
            const int g0 = eA * 16 + (t & 7) * 2;
            ((int4*)sA)[(g0)     ^ (eA & 7)] = make_int4(ow[0], ow[1], ow[2], ow[3]);
            ((int4*)sA)[(g0 + 1) ^ (eA & 7)] = make_int4(ow[4], ow[5], ow[6], ow[7]);
        }
        __syncthreads();

        f32x4 acc[2][4] = {{{0,0,0,0},{0,0,0,0},{0,0,0,0},{0,0,0,0}},
                           {{0,0,0,0},{0,0,0,0},{0,0,0,0},{0,0,0,0}}};
#pragma unroll
        for (int ks = 0; ks < 4; ++ks) {
            const int slot = ks * 4 + g;
            const bf16x8 a0 = *(const bf16x8*)&sA[(m        * 16 + (slot ^ (m & 7))) << 3];
            const bf16x8 a1 = *(const bf16x8*)&sA[((m + 16) * 16 + (slot ^ (m & 7))) << 3];
#pragma unroll
            for (int nt = 0; nt < 4; ++nt) {
                acc[0][nt] = __builtin_amdgcn_mfma_f32_16x16x32_bf16(a0, wfr[nt][ks], acc[0][nt], 0, 0, 0);
                acc[1][nt] = __builtin_amdgcn_mfma_f32_16x16x32_bf16(a1, wfr[nt][ks], acc[1][nt], 0, 0, 0);
            }
        }
#pragma unroll
        for (int mg = 0; mg < 2; ++mg)
#pragma unroll
        for (int nt = 0; nt < 4; ++nt) {
            const int n = wv * 64 + nt * 16 + m;
#pragma unroll
            for (int rg = 0; rg < 4; ++rg) {
                const int node = tbase + mg * 16 + g * 4 + rg;
                if (node < N)
                    out[(size_t)node * 256 + n] = fmaxf(acc[mg][nt][rg] + bgv[nt], 0.0f);
            }
        }
        __syncthreads();
    }
}

// ---------------------------------------------------------------------------
extern "C" void kernel_launch(void* const* d_in, const int* in_sizes, int n_in,
                              void* d_out, int out_size, void* d_ws, size_t ws_size,
                              hipStream_t stream)
{
    const float* x   = (const float*)d_in[0];
    const float* pos = (const float*)d_in[1];
    const float* W1  = (const float*)d_in[2];
    const float* b1  = (const float*)d_in[3];
    const float* W2  = (const float*)d_in[4];
    const float* b2  = (const float*)d_in[5];
    const float* Wg  = (const float*)d_in[6];
    const float* bg  = (const float*)d_in[7];
    const int*   ei  = (const int*)d_in[8];
    float* out = (float*)d_out;

    const int N    = in_sizes[1] / 3;
    const int N64  = in_sizes[0];
    const int E    = in_sizes[8] / 2;
    const int nTot = E + N;

    size_t off = 0;
    auto alloc = [&](size_t bytes) -> void* {
        void* p = (char*)d_ws + off;
        off += (bytes + 255) & ~(size_t)255;
        return p;
    };
    unsigned short* xbf  = (unsigned short*)alloc((size_t)N64 * 2);
    unsigned int*   agg  = (unsigned int*)  alloc((size_t)N * 128 * 4);
    int*            deg  = (int*)           alloc((size_t)N * 4);
    int*            offs = (int*)           alloc((size_t)N * 4);
    int2*           spair= (int2*)          alloc((size_t)nTot * 8);
    unsigned short* W2t  = (unsigned short*)alloc(16384 * 2);
    unsigned short* Wgt  = (unsigned short*)alloc(32768 * 2);
    unsigned short* W1at = (unsigned short*)alloc(8192 * 2);

    hipMemsetAsync(agg, 0, (size_t)N * 128 * 4, stream);
    hipMemsetAsync(deg, 0, (size_t)N * 4, stream);

    const int NB_X = (N64 + 2047) / 2048;
    const int NB_C = (nTot + 255) / 256;
    const int NB_T = 224;
    hipLaunchKernelGGL(prep_kernel, dim3(NB_X + NB_C + NB_T), dim3(256), 0, stream,
                       x, W1, W2, Wg, ei, xbf, W2t, Wgt, W1at, deg,
                       N64, E, nTot, NB_X, NB_C);

    hipLaunchKernelGGL(scan_kernel, dim3(1), dim3(1024), 0, stream, deg, offs, N);

    hipLaunchKernelGGL(scatter_kernel, dim3((nTot + 255) / 256), dim3(256), 0, stream,
                       ei, offs, deg, spair, E, nTot);

    const int nTilesE = (nTot + 31) / 32;
    hipLaunchKernelGGL(edge_kernel, dim3(EDGE_GRID), dim3(256), 0, stream,
                       xbf, pos, W1, b1, b2, W2t, W1at, spair, agg, nTot, nTilesE);

    const int nTilesO = (N + 31) / 32;
    hipLaunchKernelGGL(out_kernel, dim3(OUT_GRID), dim3(256), 0, stream,
                       (const float*)agg, Wgt, bg, out, N, nTilesO);
}

// Round 9
// 403.149 us; speedup vs baseline: 1.4632x; 1.4632x over previous
//
#include <hip/hip_runtime.h>
#include <hip/hip_bf16.h>

typedef __attribute__((ext_vector_type(4))) float f32x4;
typedef __attribute__((ext_vector_type(8))) short bf16x8;

#define EDGE_GRID 1024
#define OUT_GRID  1024

// RNE f32->bf16 via scalar casts: compiler fuses pairs to v_cvt_pk_bf16_f32
__device__ __forceinline__ unsigned int packbf(float lo, float hi) {
    __hip_bfloat16 l = __float2bfloat16(lo), h = __float2bfloat16(hi);
    const unsigned short lu = *reinterpret_cast<unsigned short*>(&l);
    const unsigned short hu = *reinterpret_cast<unsigned short*>(&h);
    return (unsigned int)lu | ((unsigned int)hu << 16);
}
__device__ __forceinline__ unsigned short bf1(float f) {
    __hip_bfloat16 v = __float2bfloat16(f);
    return *reinterpret_cast<unsigned short*>(&v);
}

// ---------------------------------------------------------------------------
// mega-prep: [0,NB_X) xbf = bf16(x); [NB_X,+NB_C) deg histogram;
//            [+NB_C,+224) W2t/Wgt/W1at transposes.
// ---------------------------------------------------------------------------
__global__ __launch_bounds__(256) void prep_kernel(
    const float* __restrict__ x, const float* __restrict__ W1,
    const float* __restrict__ W2, const float* __restrict__ Wg,
    const int* __restrict__ ei, unsigned short* __restrict__ xbf,
    unsigned short* __restrict__ W2t, unsigned short* __restrict__ Wgt,
    unsigned short* __restrict__ W1at, int* __restrict__ deg,
    int N64, int E, int nTot, int NB_X, int NB_C)
{
    const int blk = blockIdx.x, t = threadIdx.x;
    if (blk < NB_X) {
        const int idx = blk * 2048 + t * 8;
        if (idx < N64) {
            const float4 f0 = *(const float4*)(x + idx);
            const float4 f1 = *(const float4*)(x + idx + 4);
            int4 o;
            o.x = (int)packbf(f0.x, f0.y); o.y = (int)packbf(f0.z, f0.w);
            o.z = (int)packbf(f1.x, f1.y); o.w = (int)packbf(f1.z, f1.w);
            *(int4*)(xbf + idx) = o;
        }
    } else if (blk < NB_X + NB_C) {
        const int i = (blk - NB_X) * 256 + t;
        if (i < nTot) atomicAdd(deg + ((i < E) ? ei[i] : i - E), 1);
    } else {
        const int i = (blk - NB_X - NB_C) * 256 + t;
        if (i < 16384) {                       // W2t[n][k] = W2[k][n]
            W2t[i] = bf1(W2[(i & 127) * 128 + (i >> 7)]);
        } else if (i < 49152) {                // Wgt[n][k] = Wg[k][n]
            const int j = i - 16384;
            Wgt[j] = bf1(Wg[(j & 127) * 256 + (j >> 7)]);
        } else if (i < 57344) {                // W1at[n][k] = W1[k][n], k<64
            const int j = i - 49152;
            W1at[j] = bf1(W1[(j & 63) * 128 + (j >> 6)]);
        }
    }
}

// ---------------------------------------------------------------------------
// Single-block exclusive scan of deg[N] -> offs[N].  1024 thr x 52 elems.
// ---------------------------------------------------------------------------
__global__ __launch_bounds__(1024) void scan_kernel(
    const int* __restrict__ deg, int* __restrict__ offs, int N)
{
    __shared__ int sc[1024];
    const int t = threadIdx.x;
    const int c0 = t * 52;
    int v[52];
    int s = 0;
#pragma unroll
    for (int j4 = 0; j4 < 13; ++j4) {
        const int idx = c0 + j4 * 4;
        int4 d = {0, 0, 0, 0};
        if (idx + 3 < N) d = *(const int4*)(deg + idx);
        else {
            if (idx     < N) d.x = deg[idx];
            if (idx + 1 < N) d.y = deg[idx + 1];
            if (idx + 2 < N) d.z = deg[idx + 2];
        }
        v[j4*4+0] = s; s += d.x;
        v[j4*4+1] = s; s += d.y;
        v[j4*4+2] = s; s += d.z;
        v[j4*4+3] = s; s += d.w;
    }
    sc[t] = s;
    __syncthreads();
    for (int off = 1; off < 1024; off <<= 1) {
        const int val = (t >= off) ? sc[t - off] : 0;
        __syncthreads();
        sc[t] += val;
        __syncthreads();
    }
    const int base = sc[t] - s;
#pragma unroll
    for (int j4 = 0; j4 < 13; ++j4) {
        const int idx = c0 + j4 * 4;
        const int4 o = {base + v[j4*4], base + v[j4*4+1], base + v[j4*4+2], base + v[j4*4+3]};
        if (idx + 3 < N) *(int4*)(offs + idx) = o;
        else {
            if (idx     < N) offs[idx]     = o.x;
            if (idx + 1 < N) offs[idx + 1] = o.y;
            if (idx + 2 < N) offs[idx + 2] = o.z;
        }
    }
}

// ---------------------------------------------------------------------------
// scatter: deg doubles as cursor via atomicSub; packed (row,col) int2.
// ---------------------------------------------------------------------------
__global__ void scatter_kernel(const int* __restrict__ ei, const int* __restrict__ offs,
                               int* __restrict__ deg, int2* __restrict__ spair,
                               int E, int nTot)
{
    const int i = blockIdx.x * 256 + threadIdx.x;
    if (i < nTot) {
        int row, col;
        if (i < E) { row = ei[i]; col = ei[E + i]; }
        else       { row = col = i - E; }
        const int p = atomicSub(deg + row, 1) - 1;
        spair[offs[row] + p] = make_int2(row, col);
    }
}

// ---------------------------------------------------------------------------
// Fused edge MLP (2x bf16 MFMA) + segmented scatter-max.
// Block owns a CONTIGUOUS chunk of tiles -> its target rows are a contiguous
// ~50-row window: agg traffic is L2-local; per-column carry (cur,run) persists
// across tiles so each row is flushed once; interior rows = plain store
// (block-exclusive), chunk-boundary rows = fire-and-forget atomicMax.
// ---------------------------------------------------------------------------
__global__ __launch_bounds__(256, 4) void edge_kernel(
    const unsigned short* __restrict__ xbf, const float* __restrict__ pos,
    const float* __restrict__ W1, const float* __restrict__ b1,
    const float* __restrict__ b2, const unsigned short* __restrict__ W2t,
    const unsigned short* __restrict__ W1at, const int2* __restrict__ spair,
    unsigned int* __restrict__ agg, int nTot, int nTiles, int CPB)
{
    __shared__ unsigned short sx1[2048];   // [32 e][64 k] bf16, granule^(e&7)
    __shared__ unsigned short sh1b[4096];  // [32 e][128 h] bf16, granule^(e&7)
    __shared__ unsigned short sh2u[4096];  // [32 e][128 n] bf16, col rot +2e
    __shared__ float4 sRel4[32];
    __shared__ int sRowL[2][32];

    const int t0chunk = blockIdx.x * CPB;
    if (t0chunk >= nTiles) return;
    const int tEnd = min(t0chunk + CPB, nTiles);

    const int t = threadIdx.x;
    const int wv = t >> 6, lane = t & 63;
    const int m = lane & 15, g = lane >> 4;
    const int n0 = wv * 32 + m;
    const int e8 = t >> 3, j8 = t & 7;

    // chunk-boundary rows (shared with neighbor blocks -> atomic path)
    const int rowFirst = spair[(size_t)t0chunk * 32].x;
    const int rowLast  = spair[(size_t)min(tEnd * 32, nTot) - 1].x;

    // W2 + W1a fragments and per-col constants -> registers
    bf16x8 bfrW2[2][4], bfrA[2][2];
    float w1pv[2][3], b1v[2], b2v[2];
#pragma unroll
    for (int nb = 0; nb < 2; ++nb) {
        const int n = n0 + nb * 16;
#pragma unroll
        for (int ks = 0; ks < 4; ++ks)
            bfrW2[nb][ks] = *(const bf16x8*)(W2t + (size_t)n * 128 + (ks * 4 + g) * 8);
#pragma unroll
        for (int ks = 0; ks < 2; ++ks)
            bfrA[nb][ks] = *(const bf16x8*)(W1at + (size_t)n * 64 + (ks * 4 + g) * 8);
#pragma unroll
        for (int ax = 0; ax < 3; ++ax)
            w1pv[nb][ax] = W1[(64 + ax) * 128 + n];
        b1v[nb] = b1[n];
        b2v[nb] = b2[n];
    }

    auto gatherX = [&](int tile, uint4& xa, float& r0, float& r1, float& r2, int& rowStage) {
        xa = make_uint4(0, 0, 0, 0); r0 = r1 = r2 = 0.0f; rowStage = -1;
        if (tile < tEnd) {
            const int p = tile * 32 + e8;
            if (p < nTot) {
                const int2 pr = spair[p];                      // (row, col)
                xa = *(const uint4*)(xbf + (size_t)pr.y * 64 + j8 * 8);
                if (j8 == 0) {
                    r0 = pos[pr.y * 3 + 0] - pos[pr.x * 3 + 0];
                    r1 = pos[pr.y * 3 + 1] - pos[pr.x * 3 + 1];
                    r2 = pos[pr.y * 3 + 2] - pos[pr.x * 3 + 2];
                }
            }
            if (t < 32) {
                const int p2 = tile * 32 + t;
                rowStage = (p2 < nTot) ? spair[p2].x : -1;
            }
        }
    };
    auto stage = [&](int buf, const uint4& xa, float r0, float r1, float r2, int rowStage) {
        ((uint4*)sx1)[e8 * 8 + (j8 ^ (e8 & 7))] = xa;
        if (j8 == 0) sRel4[e8] = make_float4(r0, r1, r2, 0.0f);
        if (t < 32) sRowL[buf][t] = rowStage;
    };
    // flush col t's carry: interior rows are exclusive to this block
    auto flush = [&](int cur, float run) {
        if (cur < 0) return;
        const unsigned int bits = __float_as_uint(run);
        unsigned int* dst = agg + (size_t)cur * 128 + t;
        if (cur == rowFirst || cur == rowLast) atomicMax(dst, bits);
        else *dst = bits;
    };

    // prologue
    {
        uint4 xa; float r0, r1, r2; int rs;
        gatherX(t0chunk, xa, r0, r1, r2, rs);
        stage(0, xa, r0, r1, r2, rs);
    }
    __syncthreads();

    float run = 0.0f; int cur = -1;    // per-column carry (threads 0-127)
    int b = 0;
    for (int tile = t0chunk; tile < tEnd; ++tile, b ^= 1) {
        // ---- A: issue next tile's gathers (hidden under MFMA phases)
        uint4 xa; float r0, r1, r2; int rs;
        gatherX(tile + 1, xa, r0, r1, r2, rs);

        // ---- MFMA-1: h1 = x @ W1a  (K=64)
        f32x4 h1a[2][2] = {{{0,0,0,0},{0,0,0,0}}, {{0,0,0,0},{0,0,0,0}}};
#pragma unroll
        for (int ks = 0; ks < 2; ++ks) {
            const int slot = ks * 4 + g;
            const bf16x8 a0 = *(const bf16x8*)&sx1[(m        * 8 + (slot ^ (m & 7))) << 3];
            const bf16x8 a1 = *(const bf16x8*)&sx1[((m + 16) * 8 + (slot ^ (m & 7))) << 3];
            h1a[0][0] = __builtin_amdgcn_mfma_f32_16x16x32_bf16(a0, bfrA[0][ks], h1a[0][0], 0, 0, 0);
            h1a[0][1] = __builtin_amdgcn_mfma_f32_16x16x32_bf16(a0, bfrA[1][ks], h1a[0][1], 0, 0, 0);
            h1a[1][0] = __builtin_amdgcn_mfma_f32_16x16x32_bf16(a1, bfrA[0][ks], h1a[1][0], 0, 0, 0);
            h1a[1][1] = __builtin_amdgcn_mfma_f32_16x16x32_bf16(a1, bfrA[1][ks], h1a[1][1], 0, 0, 0);
        }
        // finish h1: + rel*W1p + b1, relu, pack bf16 into sh1b (swizzled)
#pragma unroll
        for (int hf = 0; hf < 2; ++hf)
#pragma unroll
        for (int rg = 0; rg < 4; ++rg) {
            const int e = hf * 16 + g * 4 + rg;
            const float4 rv = sRel4[e];
#pragma unroll
            for (int nb = 0; nb < 2; ++nb) {
                float h = h1a[hf][nb][rg] + rv.x * w1pv[nb][0] + rv.y * w1pv[nb][1]
                        + rv.z * w1pv[nb][2] + b1v[nb];
                h = fmaxf(h, 0.0f);
                const int hcol = n0 + nb * 16;
                sh1b[((e * 16 + ((hcol >> 3) ^ (e & 7))) << 3) + (hcol & 7)] = bf1(h);
            }
        }
        __syncthreads();   // sh1b ready; sx1/sRel4 free; prev C done

        // ---- MFMA-2: h2 = relu(h1 @ W2 + b2) -> sh2u (bf16, rotated cols)
        {
            f32x4 acc[2][2] = {{{0,0,0,0},{0,0,0,0}}, {{0,0,0,0},{0,0,0,0}}};
#pragma unroll
            for (int ks = 0; ks < 4; ++ks) {
                const int slot = ks * 4 + g;
                const bf16x8 a0 = *(const bf16x8*)&sh1b[(m        * 16 + (slot ^ (m & 7))) << 3];
                const bf16x8 a1 = *(const bf16x8*)&sh1b[((m + 16) * 16 + (slot ^ (m & 7))) << 3];
                acc[0][0] = __builtin_amdgcn_mfma_f32_16x16x32_bf16(a0, bfrW2[0][ks], acc[0][0], 0, 0, 0);
                acc[0][1] = __builtin_amdgcn_mfma_f32_16x16x32_bf16(a0, bfrW2[1][ks], acc[0][1], 0, 0, 0);
                acc[1][0] = __builtin_amdgcn_mfma_f32_16x16x32_bf16(a1, bfrW2[0][ks], acc[1][0], 0, 0, 0);
                acc[1][1] = __builtin_amdgcn_mfma_f32_16x16x32_bf16(a1, bfrW2[1][ks], acc[1][1], 0, 0, 0);
            }
#pragma unroll
            for (int hf = 0; hf < 2; ++hf)
#pragma unroll
            for (int rg = 0; rg < 4; ++rg) {
                const int e = hf * 16 + g * 4 + rg;
#pragma unroll
                for (int nb = 0; nb < 2; ++nb) {
                    const float v = fmaxf(acc[hf][nb][rg] + b2v[nb], 0.0f);
                    sh2u[e * 128 + ((n0 + nb * 16 + 2 * e) & 127)] = bf1(v);
                }
            }
        }

        // ---- D: stage next tile (sx1/sRel4 free since barrier above)
        stage(b ^ 1, xa, r0, r1, r2, rs);
        __syncthreads();   // sh2u + next stage ready

        // ---- C: carry segmented max (threads 0-127, col = t), rows sorted
        if (t < 128) {
#pragma unroll 8
            for (int i = 0; i < 32; ++i) {
                const int r = sRowL[b][i];
                if (r < 0) break;
                const unsigned short hv = sh2u[i * 128 + ((t + 2 * i) & 127)];
                const float v = __uint_as_float((unsigned int)hv << 16);
                if (r != cur) {
                    flush(cur, run);
                    cur = r; run = v;
                } else run = fmaxf(run, v);
            }
        }
    }
    if (t < 128) flush(cur, run);
}

// ---------------------------------------------------------------------------
// out = relu(agg @ Wg + bg) via bf16 MFMA; Wg fragments in registers.
// ---------------------------------------------------------------------------
__global__ __launch_bounds__(256, 4) void out_kernel(
    const float* __restrict__ agg, const unsigned short* __restrict__ Wgt,
    const float* __restrict__ bg, float* __restrict__ out, int N, int nTiles)
{
    __shared__ unsigned short sA[4096];   // [32 e][128 k] bf16, granule^(e&7)

    const int t = threadIdx.x;
    const int wv = t >> 6, lane = t & 63;
    const int m = lane & 15, g = lane >> 4;
    const int eA = t >> 3, kcA = (t & 7) * 16;

    bf16x8 wfr[4][4];
    float bgv[4];
#pragma unroll
    for (int nt = 0; nt < 4; ++nt) {
        const int n = wv * 64 + nt * 16 + m;
#pragma unroll
        for (int ks = 0; ks < 4; ++ks)
            wfr[nt][ks] = *(const bf16x8*)(Wgt + (size_t)n * 128 + (ks * 4 + g) * 8);
        bgv[nt] = bg[n];
    }

    for (int tile = blockIdx.x; tile < nTiles; tile += OUT_GRID) {
        const int tbase = tile * 32;
        {
            unsigned int ow[8] = {0,0,0,0,0,0,0,0};
            const int node = tbase + eA;
            if (node < N) {
                const float4* ap = (const float4*)(agg + (size_t)node * 128 + kcA);
#pragma unroll
                for (int j = 0; j < 4; ++j) {
                    const float4 v = ap[j];
                    ow[j * 2 + 0] = packbf(v.x, v.y);
                    ow[j * 2 + 1] = packbf(v.z, v.w);
                }
            }
            const int g0 = eA * 16 + (t & 7) * 2;
            ((int4*)sA)[(g0)     ^ (eA & 7)] = make_int4(ow[0], ow[1], ow[2], ow[3]);
            ((int4*)sA)[(g0 + 1) ^ (eA & 7)] = make_int4(ow[4], ow[5], ow[6], ow[7]);
        }
        __syncthreads();

        f32x4 acc[2][4] = {{{0,0,0,0},{0,0,0,0},{0,0,0,0},{0,0,0,0}},
                           {{0,0,0,0},{0,0,0,0},{0,0,0,0},{0,0,0,0}}};
#pragma unroll
        for (int ks = 0; ks < 4; ++ks) {
            const int slot = ks * 4 + g;
            const bf16x8 a0 = *(const bf16x8*)&sA[(m        * 16 + (slot ^ (m & 7))) << 3];
            const bf16x8 a1 = *(const bf16x8*)&sA[((m + 16) * 16 + (slot ^ (m & 7))) << 3];
#pragma unroll
            for (int nt = 0; nt < 4; ++nt) {
                acc[0][nt] = __builtin_amdgcn_mfma_f32_16x16x32_bf16(a0, wfr[nt][ks], acc[0][nt], 0, 0, 0);
                acc[1][nt] = __builtin_amdgcn_mfma_f32_16x16x32_bf16(a1, wfr[nt][ks], acc[1][nt], 0, 0, 0);
            }
        }
#pragma unroll
        for (int mg = 0; mg < 2; ++mg)
#pragma unroll
        for (int nt = 0; nt < 4; ++nt) {
            const int n = wv * 64 + nt * 16 + m;
#pragma unroll
            for (int rg = 0; rg < 4; ++rg) {
                const int node = tbase + mg * 16 + g * 4 + rg;
                if (node < N)
                    out[(size_t)node * 256 + n] = fmaxf(acc[mg][nt][rg] + bgv[nt], 0.0f);
            }
        }
        __syncthreads();
    }
}

// ---------------------------------------------------------------------------
extern "C" void kernel_launch(void* const* d_in, const int* in_sizes, int n_in,
                              void* d_out, int out_size, void* d_ws, size_t ws_size,
                              hipStream_t stream)
{
    const float* x   = (const float*)d_in[0];
    const float* pos = (const float*)d_in[1];
    const float* W1  = (const float*)d_in[2];
    const float* b1  = (const float*)d_in[3];
    const float* W2  = (const float*)d_in[4];
    const float* b2  = (const float*)d_in[5];
    const float* Wg  = (const float*)d_in[6];
    const float* bg  = (const float*)d_in[7];
    const int*   ei  = (const int*)d_in[8];
    float* out = (float*)d_out;

    const int N    = in_sizes[1] / 3;
    const int N64  = in_sizes[0];
    const int E    = in_sizes[8] / 2;
    const int nTot = E + N;

    size_t off = 0;
    auto alloc = [&](size_t bytes) -> void* {
        void* p = (char*)d_ws + off;
        off += (bytes + 255) & ~(size_t)255;
        return p;
    };
    unsigned short* xbf  = (unsigned short*)alloc((size_t)N64 * 2);
    unsigned int*   agg  = (unsigned int*)  alloc((size_t)N * 128 * 4);
    int*            deg  = (int*)           alloc((size_t)N * 4);
    int*            offs = (int*)           alloc((size_t)N * 4);
    int2*           spair= (int2*)          alloc((size_t)nTot * 8);
    unsigned short* W2t  = (unsigned short*)alloc(16384 * 2);
    unsigned short* Wgt  = (unsigned short*)alloc(32768 * 2);
    unsigned short* W1at = (unsigned short*)alloc(8192 * 2);

    hipMemsetAsync(agg, 0, (size_t)N * 128 * 4, stream);
    hipMemsetAsync(deg, 0, (size_t)N * 4, stream);

    const int NB_X = (N64 + 2047) / 2048;
    const int NB_C = (nTot + 255) / 256;
    const int NB_T = 224;
    hipLaunchKernelGGL(prep_kernel, dim3(NB_X + NB_C + NB_T), dim3(256), 0, stream,
                       x, W1, W2, Wg, ei, xbf, W2t, Wgt, W1at, deg,
                       N64, E, nTot, NB_X, NB_C);

    hipLaunchKernelGGL(scan_kernel, dim3(1), dim3(1024), 0, stream, deg, offs, N);

    hipLaunchKernelGGL(scatter_kernel, dim3((nTot + 255) / 256), dim3(256), 0, stream,
                       ei, offs, deg, spair, E, nTot);

    const int nTilesE = (nTot + 31) / 32;
    const int CPB = (nTilesE + EDGE_GRID - 1) / EDGE_GRID;
    hipLaunchKernelGGL(edge_kernel, dim3(EDGE_GRID), dim3(256), 0, stream,
                       xbf, pos, W1, b1, b2, W2t, W1at, spair, agg,
                       nTot, nTilesE, CPB);

    const int nTilesO = (N + 31) / 32;
    hipLaunchKernelGGL(out_kernel, dim3(OUT_GRID), dim3(256), 0, stream,
                       (const float*)agg, Wgt, bg, out, N, nTilesO);
}